// Round 2
// baseline (3106.569 us; speedup 1.0000x reference)
//
#include <hip/hip_runtime.h>
#include <cstdint>
#include <cstddef>

// ---------------------------------------------------------------------------
// Seq2Seq bi-GRU encoder (T=512,B=512,D=64,H=128,L=2) + 24-step GRU decoder.
// R10. Attack the per-step stall in both scans (R9: MfmaUtil 2.6%, VALUBusy
// 9.3% -> 88% stall):
//  1. RAW barriers: replace __syncthreads() (which drains vmcnt(0) = the HBM
//     prefetch + Yout store, ~1000cy/step) with
//     asm("s_waitcnt lgkmcnt(0); s_barrier") -- vmem stays in flight across
//     barriers (T3/T4 pattern). Prefetch is HELD A FULL STEP: load for step
//     s+2 issued at step s, committed to LDS at step s+1 (compiler emits a
//     counted vmcnt wait before the commit -- by then the load has landed).
//     Overlay race-freedom re-proven under relaxed barriers: every overlay
//     row's last read is consumed (vmcnt-waited into LDS) >=2 barriers before
//     the overwriting store is issued, both dirs and cross-dir.
//  2. T2 XOR swizzle on all LDS tiles (row strides 72/136/264 shorts are all
//     ==4 dw mod 32 -> 8-way conflicts on b128 frag reads; scan1 logged
//     1.26e7 conflict-cycles). col_shorts ^= ((row&7)<<3) on write AND read.
//  3. Split MFMA accumulate chains: x-part / h-part accumulate separately
//     (chain 6 -> max 4; scan1 aI 8 -> 4+4), merged at gate time.
// k_dec / k_prep / launcher unchanged (R6-verified).
// ---------------------------------------------------------------------------

typedef __attribute__((ext_vector_type(8))) short short8_t;
typedef __attribute__((ext_vector_type(4))) short short4_t;
typedef __attribute__((ext_vector_type(4))) float f32x4_t;

#define MFMA16(a, b, c) __builtin_amdgcn_mfma_f32_16x16x32_bf16((a), (b), (c), 0, 0, 0)

// raw barrier: LDS flush only, vmem ops stay in flight (no vmcnt drain)
#define BAR_LDS() asm volatile("s_waitcnt lgkmcnt(0)\n\ts_barrier" ::: "memory")

static __device__ __forceinline__ float bf2f(unsigned short u) {
  unsigned int v = ((unsigned int)u) << 16;
  return __builtin_bit_cast(float, v);
}
static __device__ __forceinline__ unsigned short f2bf(float f) {
  unsigned int x = __builtin_bit_cast(unsigned int, f);
  x += 0x7fffu + ((x >> 16) & 1u);   // round-to-nearest-even
  return (unsigned short)(x >> 16);
}
static __device__ __forceinline__ short8_t ld8(const unsigned short* p) {
  return *reinterpret_cast<const short8_t*>(p);
}
static __device__ __forceinline__ short8_t cvt8f(const float* p) {
  const f32x4_t* v = reinterpret_cast<const f32x4_t*>(p);
  f32x4_t a = v[0], b = v[1];
  short8_t r;
  r[0] = (short)f2bf(a[0]); r[1] = (short)f2bf(a[1]);
  r[2] = (short)f2bf(a[2]); r[3] = (short)f2bf(a[3]);
  r[4] = (short)f2bf(b[0]); r[5] = (short)f2bf(b[1]);
  r[6] = (short)f2bf(b[2]); r[7] = (short)f2bf(b[3]);
  return r;
}
static __device__ __forceinline__ float sigm(float x) { return 1.0f / (1.0f + __expf(-x)); }
static __device__ __forceinline__ float tanh_fast(float y) {
  float t = __expf(-2.0f * fabsf(y));
  float r = (1.0f - t) / (1.0f + t);
  return copysignf(r, y);
}

// ------------- prep: cast decoder weights, snapshot x[-1,:,0] ---------------
__global__ void k_prep(const float* __restrict__ x,
                       const float* __restrict__ dWih1, const float* __restrict__ dWhh,
                       unsigned short* __restrict__ bdWih1, unsigned short* __restrict__ bdWhh,
                       float* __restrict__ x0save) {
  const int NW = 24576;   // 196608 elems / 8
  int i = blockIdx.x * blockDim.x + threadIdx.x;
  if (i < NW) {
    *reinterpret_cast<short8_t*>(bdWih1 + (size_t)i * 8) = cvt8f(dWih1 + (size_t)i * 8);
  } else if (i < 2 * NW) {
    int j = i - NW;
    *reinterpret_cast<short8_t*>(bdWhh + (size_t)j * 8) = cvt8f(dWhh + (size_t)j * 8);
  } else if (i < 2 * NW + 512) {
    int b = i - 2 * NW;
    x0save[b] = x[((size_t)511 * 512 + b) * 64];
  }
}

// ---- layer-0 scan, BOTH dirs in one block, gi fused (K=64), pipelined ------
// grid (Bc/16). Block = 16 batch rows x 2 dirs, 8 waves (0-3 fwd, 4-7 bwd);
// within a dir, wave w owns h-cols [w*32,w*32+32). Double-buffered per-dir
// xl/hl, one RAW barrier/step, x prefetch held a full step. Output routing:
//   fwd: t<256 -> wsF,  t>=256 -> x overlay
//   bwd: t<256 -> x overlay, t>=256 -> wsB
// LDS swizzle: col_shorts ^= ((row&7)<<3) on every tile access (T2).
__global__ __launch_bounds__(512, 1) void k_scan0m(
    float* x,                               // (512,512,64) fp32, overlaid
    const float* __restrict__ Wih,          // enc_Wih0 (2,384,64) fp32
    const float* __restrict__ bih,          // (2,384) layer0
    const float* __restrict__ Whh,          // (2,384,128) layer0
    const float* __restrict__ bhh,          // (2,384) layer0
    unsigned short* __restrict__ wsF,       // (256,Bc,128) bf16: OutF t<256
    unsigned short* __restrict__ wsB,       // (256,Bc,128) bf16: OutB t>=256
    float* __restrict__ HS,                 // (4,512,128) fp32
    int b_base, int Bc) {
  int b0 = b_base + blockIdx.x * 16;
  int bl0 = blockIdx.x * 16;                // chunk-local batch base
  int tid = threadIdx.x;
  int dir = tid >> 8;                       // waves 0-3: fwd, 4-7: bwd
  int tl = tid & 255;
  int w = tl >> 6, lane = tl & 63, q = lane >> 4, c16 = lane & 15;
  __shared__ unsigned short xl[2][2][16 * 72];    // [dir][buf], +8 pad
  __shared__ unsigned short hl[2][2][16 * 136];   // [dir][buf], +8 pad
  const float* Wi = Wih + (size_t)dir * 384 * 64;
  const float* Wh = Whh + (size_t)dir * 384 * 128;
  const float* bi = bih + dir * 384;
  const float* bh = bhh + dir * 384;

  short8_t fi[6][2], fh[6][4];
  float brz[4], bni[2], bnh[2];
#pragma unroll
  for (int g = 0; g < 3; g++)
#pragma unroll
    for (int cc = 0; cc < 2; cc++) {
      int f = g * 2 + cc;
      int n0 = g * 128 + w * 32 + cc * 16;
#pragma unroll
      for (int kt = 0; kt < 2; kt++)
        fi[f][kt] = cvt8f(Wi + (size_t)(n0 + c16) * 64 + kt * 32 + q * 8);
#pragma unroll
      for (int kt = 0; kt < 4; kt++)
        fh[f][kt] = cvt8f(Wh + (size_t)(n0 + c16) * 128 + kt * 32 + q * 8);
      if (g < 2) brz[f] = bi[n0 + c16] + bh[n0 + c16];
      else { bni[cc] = bi[n0 + c16]; bnh[cc] = bh[n0 + c16]; }
    }

  float h[2][4];
#pragma unroll
  for (int cc = 0; cc < 2; cc++)
#pragma unroll
    for (int rr = 0; rr < 4; rr++) h[cc][rr] = 0.f;
  for (int i = tl; i < 16 * 136; i += 256) hl[dir][0][i] = 0;

  int srow = tl >> 4, sc = tl & 15;            // staging/writeback roles
  {                                            // stage xl[dir][0] for first t
    int t0 = dir ? 511 : 0;
    f32x4_t v = *reinterpret_cast<const f32x4_t*>(
        x + ((size_t)t0 * 512 + b0 + srow) * 64 + sc * 4);
    unsigned short* dst = &xl[dir][0][srow * 72 + ((sc * 4) ^ ((srow & 7) << 3))];
    dst[0] = f2bf(v[0]); dst[1] = f2bf(v[1]); dst[2] = f2bf(v[2]); dst[3] = f2bf(v[3]);
  }
  f32x4_t xv;                                  // held x tile for step s+1
  {
    int t1 = dir ? 510 : 1;
    xv = *reinterpret_cast<const f32x4_t*>(
        x + ((size_t)t1 * 512 + b0 + srow) * 64 + sc * 4);
  }
  __syncthreads();                             // full drain once (prologue)

  for (int s = 0; s < 512; s++) {
    int cur = s & 1, nxt = cur ^ 1;
    if (s < 511) {                             // commit held x tile (step s+1)
      unsigned short* dst = &xl[dir][nxt][srow * 72 + ((sc * 4) ^ ((srow & 7) << 3))];
      dst[0] = f2bf(xv[0]); dst[1] = f2bf(xv[1]); dst[2] = f2bf(xv[2]); dst[3] = f2bf(xv[3]);
    }
    if (s < 510) {                             // issue load for step s+2
      int tn = dir ? (509 - s) : (s + 2);
      xv = *reinterpret_cast<const f32x4_t*>(
          x + ((size_t)tn * 512 + b0 + srow) * 64 + sc * 4);
    }
    if (s > 0) {                               // Yout for h(s-1), from hl[cur]
      int tp = dir ? (512 - s) : (s - 1);
      short8_t v = ld8(&hl[dir][cur][srow * 136 + ((sc * 8) ^ ((srow & 7) << 3))]);
      unsigned short* dst;
      bool tox = dir ? (tp < 256) : (tp >= 256);
      if (tox)
        dst = (unsigned short*)x + ((size_t)tp * 512 + b0 + srow) * 128 + sc * 8;
      else if (dir)
        dst = wsB + ((size_t)(tp - 256) * Bc + bl0 + srow) * 128 + sc * 8;
      else
        dst = wsF + ((size_t)tp * Bc + bl0 + srow) * 128 + sc * 8;
      *reinterpret_cast<short8_t*>(dst) = v;
    }
    short8_t ax[2], ah[4];
#pragma unroll
    for (int kt = 0; kt < 2; kt++)
      ax[kt] = ld8(&xl[dir][cur][c16 * 72 + ((kt * 32 + q * 8) ^ ((c16 & 7) << 3))]);
#pragma unroll
    for (int kt = 0; kt < 4; kt++)
      ah[kt] = ld8(&hl[dir][cur][c16 * 136 + ((kt * 32 + q * 8) ^ ((c16 & 7) << 3))]);
    f32x4_t aRZ[4], aRZh[4], aNi[2], aNh[2];   // split x/h accumulate chains
#pragma unroll
    for (int f = 0; f < 4; f++) {
      aRZ[f] = (f32x4_t){0.f, 0.f, 0.f, 0.f};
      aRZh[f] = (f32x4_t){0.f, 0.f, 0.f, 0.f};
    }
#pragma unroll
    for (int cc = 0; cc < 2; cc++) {
      aNi[cc] = (f32x4_t){0.f, 0.f, 0.f, 0.f};
      aNh[cc] = (f32x4_t){0.f, 0.f, 0.f, 0.f};
    }
#pragma unroll
    for (int kt = 0; kt < 2; kt++) {
#pragma unroll
      for (int f = 0; f < 4; f++) aRZ[f] = MFMA16(ax[kt], fi[f][kt], aRZ[f]);
#pragma unroll
      for (int cc = 0; cc < 2; cc++) aNi[cc] = MFMA16(ax[kt], fi[4 + cc][kt], aNi[cc]);
    }
#pragma unroll
    for (int kt = 0; kt < 4; kt++) {
#pragma unroll
      for (int f = 0; f < 4; f++) aRZh[f] = MFMA16(ah[kt], fh[f][kt], aRZh[f]);
#pragma unroll
      for (int cc = 0; cc < 2; cc++) aNh[cc] = MFMA16(ah[kt], fh[4 + cc][kt], aNh[cc]);
    }
#pragma unroll
    for (int cc = 0; cc < 2; cc++)
#pragma unroll
      for (int rr = 0; rr < 4; rr++) {
        float r = sigm(aRZ[cc][rr] + aRZh[cc][rr] + brz[cc]);
        float z = sigm(aRZ[2 + cc][rr] + aRZh[2 + cc][rr] + brz[2 + cc]);
        float n = tanh_fast(aNi[cc][rr] + bni[cc] + r * (aNh[cc][rr] + bnh[cc]));
        float hn = n + z * (h[cc][rr] - n);
        h[cc][rr] = hn;
        int row = q * 4 + rr, col = w * 32 + c16 + cc * 16;
        hl[dir][nxt][row * 136 + (col ^ ((row & 7) << 3))] = f2bf(hn);
      }
    BAR_LDS();
  }
  {                                            // final Yout row (step 511's h in hl[0])
    int tp = dir ? 0 : 511;                    // both go to the x overlay
    short8_t v = ld8(&hl[dir][0][srow * 136 + ((sc * 8) ^ ((srow & 7) << 3))]);
    *reinterpret_cast<short8_t*>(
        (unsigned short*)x + ((size_t)tp * 512 + b0 + srow) * 128 + sc * 8) = v;
  }
#pragma unroll
  for (int cc = 0; cc < 2; cc++)
#pragma unroll
    for (int rr = 0; rr < 4; rr++)
      HS[((size_t)dir * 512 + b0 + q * 4 + rr) * 128 + w * 32 + c16 + cc * 16] = h[cc][rr];
}

// input selector for layer 1: cols [0,128) = OutF, [128,256) = OutB; each is
// split per-t between a ws buffer and the x overlay (see k_scan0m header).
static __device__ __forceinline__ short8_t ld_l1in(
    const unsigned short* __restrict__ wsF, const unsigned short* __restrict__ wsB,
    const unsigned short* __restrict__ xo, int t, int Bc, int b_base,
    int brl, int sc) {
  size_t xrow = ((size_t)t * 512 + b_base + brl) * 128;
  if (sc < 16) {                               // OutF half
    const unsigned short* p = (t >= 256)
        ? xo + xrow + sc * 8
        : wsF + ((size_t)t * Bc + brl) * 128 + sc * 8;
    return ld8(p);
  }
  int c = sc - 16;                             // OutB half
  const unsigned short* p = (t < 256)
      ? xo + xrow + c * 8
      : wsB + ((size_t)(t - 256) * Bc + brl) * 128 + c * 8;
  return ld8(p);
}

// ---- layer-1 scan, gi fused (K=256 = [OutF||OutB]), both dirs, pipelined ---
// grid (Bc/16, 2). Block = 512 thr (8 waves); wave w owns h-cols [w*16,+16).
// Same RAW-barrier + held-prefetch + swizzle treatment as k_scan0m.
__global__ __launch_bounds__(512, 1) void k_scan1(
    const unsigned short* __restrict__ wsF,
    const unsigned short* __restrict__ wsB,
    const unsigned short* __restrict__ xo,    // x overlay as bf16 rows
    const float* __restrict__ Wih1,           // enc_Wih1 (2,384,256) fp32
    const float* __restrict__ bih1,           // (2,384) layer1
    const float* __restrict__ Whh1,           // (2,384,128) layer1
    const float* __restrict__ bhh1,           // (2,384) layer1
    float* __restrict__ HS,
    int b_base, int Bc) {
  int dir = blockIdx.y;
  int b0l = blockIdx.x * 16;
  int tid = threadIdx.x, w = tid >> 6, lane = tid & 63, q = lane >> 4, c16 = lane & 15;
  __shared__ unsigned short il[2][16 * 264];   // input tile (256 + 8 pad)
  __shared__ unsigned short hl[2][16 * 136];
  const float* Wi = Wih1 + (size_t)dir * 384 * 256;
  const float* Wh = Whh1 + (size_t)dir * 384 * 128;
  const float* bi = bih1 + dir * 384;
  const float* bh = bhh1 + dir * 384;

  short8_t fi[3][8], fh[3][4];
  float brz[2], bni, bnh;
#pragma unroll
  for (int g = 0; g < 3; g++) {
    int n0 = g * 128 + w * 16;
#pragma unroll
    for (int kt = 0; kt < 8; kt++)
      fi[g][kt] = cvt8f(Wi + (size_t)(n0 + c16) * 256 + kt * 32 + q * 8);
#pragma unroll
    for (int kt = 0; kt < 4; kt++)
      fh[g][kt] = cvt8f(Wh + (size_t)(n0 + c16) * 128 + kt * 32 + q * 8);
    if (g < 2) brz[g] = bi[n0 + c16] + bh[n0 + c16];
    else { bni = bi[n0 + c16]; bnh = bh[n0 + c16]; }
  }

  float h[4] = {0.f, 0.f, 0.f, 0.f};
  for (int i = tid; i < 16 * 136; i += 512) hl[0][i] = 0;

  int srow = tid >> 5, sc = tid & 31;          // staging: 16 rows x 32 col-chunks
  {                                            // stage il[0] for first t
    int t0 = dir ? 511 : 0;
    short8_t v = ld_l1in(wsF, wsB, xo, t0, Bc, b_base, b0l + srow, sc);
    *reinterpret_cast<short8_t*>(
        &il[0][srow * 264 + ((sc * 8) ^ ((srow & 7) << 3))]) = v;
  }
  short8_t iv;                                 // held input tile for step s+1
  {
    int t1 = dir ? 510 : 1;
    iv = ld_l1in(wsF, wsB, xo, t1, Bc, b_base, b0l + srow, sc);
  }
  __syncthreads();                             // full drain once (prologue)

  for (int s = 0; s < 512; s++) {
    int cur = s & 1, nxt = cur ^ 1;
    if (s < 511)                               // commit held tile (step s+1)
      *reinterpret_cast<short8_t*>(
          &il[nxt][srow * 264 + ((sc * 8) ^ ((srow & 7) << 3))]) = iv;
    if (s < 510) {                             // issue load for step s+2
      int tn = dir ? (509 - s) : (s + 2);
      iv = ld_l1in(wsF, wsB, xo, tn, Bc, b_base, b0l + srow, sc);
    }
    f32x4_t aIa[3], aIb[3], aH[3];             // split 8-deep aI chain 4+4
#pragma unroll
    for (int g = 0; g < 3; g++) {
      aIa[g] = (f32x4_t){0.f, 0.f, 0.f, 0.f};
      aIb[g] = (f32x4_t){0.f, 0.f, 0.f, 0.f};
      aH[g] = (f32x4_t){0.f, 0.f, 0.f, 0.f};
    }
#pragma unroll
    for (int kt = 0; kt < 8; kt++) {
      short8_t a = ld8(&il[cur][c16 * 264 + ((kt * 32 + q * 8) ^ ((c16 & 7) << 3))]);
#pragma unroll
      for (int g = 0; g < 3; g++) {
        if (kt < 4) aIa[g] = MFMA16(a, fi[g][kt], aIa[g]);
        else        aIb[g] = MFMA16(a, fi[g][kt], aIb[g]);
      }
    }
#pragma unroll
    for (int kt = 0; kt < 4; kt++) {
      short8_t a = ld8(&hl[cur][c16 * 136 + ((kt * 32 + q * 8) ^ ((c16 & 7) << 3))]);
#pragma unroll
      for (int g = 0; g < 3; g++) aH[g] = MFMA16(a, fh[g][kt], aH[g]);
    }
#pragma unroll
    for (int rr = 0; rr < 4; rr++) {
      float gI0 = aIa[0][rr] + aIb[0][rr], gI1 = aIa[1][rr] + aIb[1][rr];
      float gI2 = aIa[2][rr] + aIb[2][rr];
      float r = sigm(gI0 + aH[0][rr] + brz[0]);
      float z = sigm(gI1 + aH[1][rr] + brz[1]);
      float n = tanh_fast(gI2 + bni + r * (aH[2][rr] + bnh));
      float hn = n + z * (h[rr] - n);
      h[rr] = hn;
      int row = q * 4 + rr, col = w * 16 + c16;
      hl[nxt][row * 136 + (col ^ ((row & 7) << 3))] = f2bf(hn);
    }
    BAR_LDS();
  }
#pragma unroll
  for (int rr = 0; rr < 4; rr++)
    HS[((size_t)(2 + dir) * 512 + b_base + b0l + q * 4 + rr) * 128 + w * 16 + c16] = h[rr];
}

// ------------------------------- decoder (verified R6) ----------------------
__global__ __launch_bounds__(256, 1) void k_dec(
    const float* __restrict__ x0save,        // (512)
    const float* __restrict__ HS,            // (4,512,128) = [l0f,l0b,l1f,l1b]
    const unsigned short* __restrict__ Whh,  // dec (2,2,384,128) bf16
    const unsigned short* __restrict__ Wih1, // dec (2,384,256) bf16
    const float* __restrict__ Wih0,          // dec (2,384,1) fp32
    const float* __restrict__ bih,           // (2,2,384)
    const float* __restrict__ bhh,           // (2,2,384)
    const float* __restrict__ fc_w,          // (256) fp32
    const float* __restrict__ fcb,           // (1)
    float* __restrict__ out) {               // (24,512)
  int b0 = blockIdx.x * 16;
  int tid = threadIdx.x, w = tid >> 6, lane = tid & 63, q = lane >> 4, c16 = lane & 15;
  __shared__ unsigned short hc0[16 * 264];
  __shared__ unsigned short hc1[16 * 264];
  __shared__ float x0s[16];
  __shared__ float fcwf[256];
  int jj = w * 32 + c16;   // actual h-column (biases, LDS addressing)
  int jw = w * 32;         // wave column base (MFMA B-frag row bases; +c16 at load)

  float hs[4][2][4];
#pragma unroll
  for (int cell = 0; cell < 4; cell++)
#pragma unroll
    for (int cc = 0; cc < 2; cc++)
#pragma unroll
      for (int rr = 0; rr < 4; rr++) {
        int row = q * 4 + rr, j = jj + cc * 16;
        float v = HS[((size_t)cell * 512 + b0 + row) * 128 + j];
        hs[cell][cc][rr] = v;
        unsigned short bv = f2bf(v);
        unsigned short* tile = (cell < 2) ? hc0 : hc1;
        tile[row * 264 + (cell & 1) * 128 + j] = bv;
      }
  if (tid < 16) x0s[tid] = x0save[b0 + tid];
  fcwf[tid] = fc_w[tid];

  float w0c[2][2][3], bi0[2][2][3], bh0[2][2][3], bi1[2][2][3], bh1[2][2][3];
#pragma unroll
  for (int d = 0; d < 2; d++)
#pragma unroll
    for (int cc = 0; cc < 2; cc++)
#pragma unroll
      for (int g = 0; g < 3; g++) {
        int col = g * 128 + jj + cc * 16;
        w0c[d][cc][g] = Wih0[d * 384 + col];
        bi0[d][cc][g] = bih[d * 384 + col];
        bh0[d][cc][g] = bhh[d * 384 + col];
        bi1[d][cc][g] = bih[(2 + d) * 384 + col];
        bh1[d][cc][g] = bhh[(2 + d) * 384 + col];
      }
  __syncthreads();

  for (int st = 0; st < 24; st++) {
    // ---- layer 0 (input = scalar x0, two cells) ----
    float hn0[2][2][4];
#pragma unroll
    for (int d = 0; d < 2; d++) {
      const unsigned short* Wd = Whh + (size_t)d * 384 * 128;
      short8_t a0[4];
#pragma unroll
      for (int kt = 0; kt < 4; kt++)
        a0[kt] = ld8(&hc0[c16 * 264 + d * 128 + kt * 32 + q * 8]);
      f32x4_t acc[6];
#pragma unroll
      for (int f = 0; f < 6; f++) acc[f] = (f32x4_t){0.f, 0.f, 0.f, 0.f};
#pragma unroll
      for (int kt = 0; kt < 4; kt++)
#pragma unroll
        for (int g = 0; g < 3; g++)
#pragma unroll
          for (int cc = 0; cc < 2; cc++) {
            int f = g * 2 + cc, n0 = g * 128 + jw + cc * 16;
            acc[f] = MFMA16(a0[kt], ld8(Wd + (size_t)(n0 + c16) * 128 + kt * 32 + q * 8), acc[f]);
          }
#pragma unroll
      for (int cc = 0; cc < 2; cc++)
#pragma unroll
        for (int rr = 0; rr < 4; rr++) {
          float xin = x0s[q * 4 + rr];
          float r = sigm(xin * w0c[d][cc][0] + bi0[d][cc][0] + acc[cc][rr] + bh0[d][cc][0]);
          float z = sigm(xin * w0c[d][cc][1] + bi0[d][cc][1] + acc[2 + cc][rr] + bh0[d][cc][1]);
          float n = tanh_fast(xin * w0c[d][cc][2] + bi0[d][cc][2] +
                              r * (acc[4 + cc][rr] + bh0[d][cc][2]));
          float hv = n + z * (hs[d][cc][rr] - n);
          hn0[d][cc][rr] = hv;
          hs[d][cc][rr] = hv;
        }
    }
    __syncthreads();
#pragma unroll
    for (int d = 0; d < 2; d++)
#pragma unroll
      for (int cc = 0; cc < 2; cc++)
#pragma unroll
        for (int rr = 0; rr < 4; rr++)
          hc0[(q * 4 + rr) * 264 + d * 128 + jj + cc * 16] = f2bf(hn0[d][cc][rr]);
    __syncthreads();

    // ---- layer 1 (input = hc0 concat, two cells) ----
    short8_t ai[8];
#pragma unroll
    for (int kt = 0; kt < 8; kt++) ai[kt] = ld8(&hc0[c16 * 264 + kt * 32 + q * 8]);
    float hn1[2][2][4];
#pragma unroll
    for (int d = 0; d < 2; d++) {
      const unsigned short* Wh = Whh + (size_t)(2 + d) * 384 * 128;
      const unsigned short* Wi = Wih1 + (size_t)d * 384 * 256;
      short8_t ah[4];
#pragma unroll
      for (int kt = 0; kt < 4; kt++)
        ah[kt] = ld8(&hc1[c16 * 264 + d * 128 + kt * 32 + q * 8]);
      f32x4_t aRZ[4], aNi[2], aNh[2];
#pragma unroll
      for (int f = 0; f < 4; f++) aRZ[f] = (f32x4_t){0.f, 0.f, 0.f, 0.f};
#pragma unroll
      for (int cc = 0; cc < 2; cc++) {
        aNi[cc] = (f32x4_t){0.f, 0.f, 0.f, 0.f};
        aNh[cc] = (f32x4_t){0.f, 0.f, 0.f, 0.f};
      }
#pragma unroll
      for (int kt = 0; kt < 8; kt++) {
#pragma unroll
        for (int f = 0; f < 4; f++) {
          int n0 = (f >> 1) * 128 + jw + (f & 1) * 16;
          aRZ[f] = MFMA16(ai[kt], ld8(Wi + (size_t)(n0 + c16) * 256 + kt * 32 + q * 8), aRZ[f]);
        }
#pragma unroll
        for (int cc = 0; cc < 2; cc++) {
          int n0 = 256 + jw + cc * 16;
          aNi[cc] = MFMA16(ai[kt], ld8(Wi + (size_t)(n0 + c16) * 256 + kt * 32 + q * 8), aNi[cc]);
        }
      }
#pragma unroll
      for (int kt = 0; kt < 4; kt++) {
#pragma unroll
        for (int f = 0; f < 4; f++) {
          int n0 = (f >> 1) * 128 + jw + (f & 1) * 16;
          aRZ[f] = MFMA16(ah[kt], ld8(Wh + (size_t)(n0 + c16) * 128 + kt * 32 + q * 8), aRZ[f]);
        }
#pragma unroll
        for (int cc = 0; cc < 2; cc++) {
          int n0 = 256 + jw + cc * 16;
          aNh[cc] = MFMA16(ah[kt], ld8(Wh + (size_t)(n0 + c16) * 128 + kt * 32 + q * 8), aNh[cc]);
        }
      }
#pragma unroll
      for (int cc = 0; cc < 2; cc++)
#pragma unroll
        for (int rr = 0; rr < 4; rr++) {
          float r = sigm(aRZ[cc][rr] + bi1[d][cc][0] + bh1[d][cc][0]);
          float z = sigm(aRZ[2 + cc][rr] + bi1[d][cc][1] + bh1[d][cc][1]);
          float n = tanh_fast(aNi[cc][rr] + bi1[d][cc][2] + r * (aNh[cc][rr] + bh1[d][cc][2]));
          float hv = n + z * (hs[2 + d][cc][rr] - n);
          hn1[d][cc][rr] = hv;
          hs[2 + d][cc][rr] = hv;
        }
    }
    __syncthreads();
#pragma unroll
    for (int d = 0; d < 2; d++)
#pragma unroll
      for (int cc = 0; cc < 2; cc++)
#pragma unroll
        for (int rr = 0; rr < 4; rr++)
          hc1[(q * 4 + rr) * 264 + d * 128 + jj + cc * 16] = f2bf(hn1[d][cc][rr]);
    __syncthreads();

    // ---- fc -> pred, feed back (wave 0 only) ----
    if (w == 0) {
      float s = 0.f;
#pragma unroll
      for (int i = 0; i < 8; i++) {
        short8_t hv = ld8(&hc1[c16 * 264 + q * 64 + i * 8]);
#pragma unroll
        for (int e = 0; e < 8; e++)
          s += bf2f((unsigned short)hv[e]) * fcwf[q * 64 + i * 8 + e];
      }
      s += __shfl_xor(s, 16);
      s += __shfl_xor(s, 32);
      if (q == 0) {
        float pred = s + fcb[0];
        x0s[c16] = pred;
        out[(size_t)st * 512 + b0 + c16] = pred;
      }
    }
    __syncthreads();
  }
}

// ---------------------------------------------------------------------------
extern "C" void kernel_launch(void* const* d_in, const int* in_sizes, int n_in,
                              void* d_out, int out_size, void* d_ws, size_t ws_size,
                              hipStream_t stream) {
  const float* x     = (const float*)d_in[0];
  const float* eWih0 = (const float*)d_in[1];
  const float* eWih1 = (const float*)d_in[2];
  const float* eWhh  = (const float*)d_in[3];
  const float* ebih  = (const float*)d_in[4];
  const float* ebhh  = (const float*)d_in[5];
  const float* dWih0 = (const float*)d_in[6];
  const float* dWih1 = (const float*)d_in[7];
  const float* dWhh  = (const float*)d_in[8];
  const float* dbih  = (const float*)d_in[9];
  const float* dbhh  = (const float*)d_in[10];
  const float* fc_w  = (const float*)d_in[11];
  const float* fc_b  = (const float*)d_in[12];
  float* out = (float*)d_out;
  (void)in_sizes; (void)n_in; (void)out_size;

  // ---- ws ladder: wsF+wsB = 2 * Bc*65536 bytes (256 t-rows each) ----------
  // Bc=512 total 68.95MB == the previously-passing budget; else Bc=256 (35.4MB)
  const size_t fixedB = 2048 + 1048576 + 393216 + 393216 + 4096;
  int Bc = 256;
  if (fixedB + (size_t)2 * 512 * 65536 <= ws_size) Bc = 512;

  char* ws = (char*)d_ws;
  size_t off = 0;
  auto alloc = [&](size_t bytes) -> char* {
    off = (off + 255) & ~(size_t)255;
    char* p = ws + off;
    off += bytes;
    return p;
  };
  float* x0save          = (float*)alloc(2048);
  float* HS              = (float*)alloc(1048576);
  unsigned short* bdWih1 = (unsigned short*)alloc(393216);   // 196608 elems
  unsigned short* bdWhh  = (unsigned short*)alloc(393216);   // 196608 elems
  unsigned short* wsF    = (unsigned short*)alloc((size_t)Bc * 65536);
  unsigned short* wsB    = (unsigned short*)alloc((size_t)Bc * 65536);

  k_prep<<<194, 256, 0, stream>>>(x, dWih1, dWhh, bdWih1, bdWhh, x0save);

  float* xm = (float*)d_in[0];   // mutable view: overlay target
  const float* Whh1 = eWhh + (size_t)2 * 384 * 128;
  int nchunks = 512 / Bc;
  for (int c = 0; c < nchunks; c++) {
    int b_base = c * Bc;
    k_scan0m<<<dim3(Bc / 16), 512, 0, stream>>>(xm, eWih0, ebih, eWhh, ebhh,
                                                wsF, wsB, HS, b_base, Bc);
    k_scan1<<<dim3(Bc / 16, 2), 512, 0, stream>>>(wsF, wsB,
                                                  (const unsigned short*)xm,
                                                  eWih1, ebih + 768, Whh1,
                                                  ebhh + 768, HS, b_base, Bc);
  }
  k_dec<<<dim3(32), 256, 0, stream>>>(x0save, HS, bdWhh, bdWih1, dWih0, dbih, dbhh,
                                      fc_w, fc_b, out);
}

// Round 3
// 2156.678 us; speedup vs baseline: 1.4404x; 1.4404x over previous
//
#include <hip/hip_runtime.h>
#include <cstdint>
#include <cstddef>

// ---------------------------------------------------------------------------
// Seq2Seq bi-GRU encoder (T=512,B=512,D=64,H=128,L=2) + 24-step GRU decoder.
// R11. Revert R10's swizzle (+3.3x conflicts: the +8-short padding already
// skews banks) and raw-barrier pipeline (lengthened the serial chain) -- all
// scan bodies are R8's proven ones. Structural change instead: scan0 dirs run
// as SEPARATE 4-wave blocks (blockIdx.y=dir, 64 blocks concurrent on 64 CUs)
// rather than R9's 8-wave merged block (32 CUs, 1.7x step latency). The
// cross-block x-overlay race is eliminated by PRIVATE buffers per dir:
//   k_copy: x -> xc (ws, 67.1MB, ~25us)
//   fwd: reads x,  overlays x  with OutF (row t: read @step t-1, write @t+1)
//   bwd: reads xc, overlays xc with OutB (row t: read @510-t,   write @512-t)
// Both gaps are barrier-drained => race-free with no cross-block assumptions.
// ws = 1.84MB fixed + 67.1MB xc = 68.95MB == previously-passing budget.
// scan1 input addressing now branch-free (OutF=x stride 512, OutB=xc stride
// Bc). k_dec / k_prep unchanged (R6-verified).
// ---------------------------------------------------------------------------

typedef __attribute__((ext_vector_type(8))) short short8_t;
typedef __attribute__((ext_vector_type(4))) short short4_t;
typedef __attribute__((ext_vector_type(4))) float f32x4_t;

#define MFMA16(a, b, c) __builtin_amdgcn_mfma_f32_16x16x32_bf16((a), (b), (c), 0, 0, 0)

static __device__ __forceinline__ float bf2f(unsigned short u) {
  unsigned int v = ((unsigned int)u) << 16;
  return __builtin_bit_cast(float, v);
}
static __device__ __forceinline__ unsigned short f2bf(float f) {
  unsigned int x = __builtin_bit_cast(unsigned int, f);
  x += 0x7fffu + ((x >> 16) & 1u);   // round-to-nearest-even
  return (unsigned short)(x >> 16);
}
static __device__ __forceinline__ short8_t ld8(const unsigned short* p) {
  return *reinterpret_cast<const short8_t*>(p);
}
static __device__ __forceinline__ short8_t cvt8f(const float* p) {
  const f32x4_t* v = reinterpret_cast<const f32x4_t*>(p);
  f32x4_t a = v[0], b = v[1];
  short8_t r;
  r[0] = (short)f2bf(a[0]); r[1] = (short)f2bf(a[1]);
  r[2] = (short)f2bf(a[2]); r[3] = (short)f2bf(a[3]);
  r[4] = (short)f2bf(b[0]); r[5] = (short)f2bf(b[1]);
  r[6] = (short)f2bf(b[2]); r[7] = (short)f2bf(b[3]);
  return r;
}
static __device__ __forceinline__ float sigm(float x) { return 1.0f / (1.0f + __expf(-x)); }
static __device__ __forceinline__ float tanh_fast(float y) {
  float t = __expf(-2.0f * fabsf(y));
  float r = (1.0f - t) / (1.0f + t);
  return copysignf(r, y);
}

// ------------- prep: cast decoder weights, snapshot x[-1,:,0] ---------------
__global__ void k_prep(const float* __restrict__ x,
                       const float* __restrict__ dWih1, const float* __restrict__ dWhh,
                       unsigned short* __restrict__ bdWih1, unsigned short* __restrict__ bdWhh,
                       float* __restrict__ x0save) {
  const int NW = 24576;   // 196608 elems / 8
  int i = blockIdx.x * blockDim.x + threadIdx.x;
  if (i < NW) {
    *reinterpret_cast<short8_t*>(bdWih1 + (size_t)i * 8) = cvt8f(dWih1 + (size_t)i * 8);
  } else if (i < 2 * NW) {
    int j = i - NW;
    *reinterpret_cast<short8_t*>(bdWhh + (size_t)j * 8) = cvt8f(dWhh + (size_t)j * 8);
  } else if (i < 2 * NW + 512) {
    int b = i - 2 * NW;
    x0save[b] = x[((size_t)511 * 512 + b) * 64];
  }
}

// ------------- copy chunk of x into ws (bwd's private read+overlay buffer) --
__global__ void k_copy(const float* __restrict__ x, float* __restrict__ xc,
                       int b_base, int Bc) {
  size_t i = (size_t)blockIdx.x * blockDim.x + threadIdx.x;
  size_t per = (size_t)Bc * 16;            // float4s per t-slab
  size_t n = (size_t)512 * per;
  if (i >= n) return;
  size_t t = i / per, r = i - t * per;
  const f32x4_t* s =
      reinterpret_cast<const f32x4_t*>(x + ((size_t)t * 512 + b_base) * 64) + r;
  f32x4_t* d = reinterpret_cast<f32x4_t*>(xc + t * per * 4) + r;
  *d = *s;
}

// ---- layer-0 scan, one dir per block (blockIdx.y), gi fused (K=64) ---------
// grid (Bc/16, 2). Block = 16 batch rows, 4 waves; wave w owns h-cols
// [w*32,w*32+32). Double-buffered xl/hl, ONE barrier/step, x prefetched.
// Each dir reads AND overlays its own private buffer (fwd: x, bwd: xc) --
// write of row t is >=2 barrier-drained steps after its last read.
__global__ __launch_bounds__(256, 1) void k_scan0d(
    float* x,                               // (512,512,64) fp32; fwd in+out
    float* xc,                              // (512,Bc,64) fp32 copy; bwd in+out
    const float* __restrict__ Wih,          // enc_Wih0 (2,384,64) fp32
    const float* __restrict__ bih,          // (2,384) layer0
    const float* __restrict__ Whh,          // (2,384,128) layer0
    const float* __restrict__ bhh,          // (2,384) layer0
    float* __restrict__ HS,                 // (4,512,128) fp32
    int b_base, int Bc) {
  int dir = blockIdx.y;
  int bl0 = blockIdx.x * 16;                // chunk-local batch base
  int b0g = b_base + bl0;                   // global batch base
  float* xin = dir ? xc : x;                // private read+overlay buffer
  unsigned short* yout = (unsigned short*)xin;
  int xstr = dir ? Bc : 512;                // row stride in that buffer
  int xb0 = dir ? bl0 : b0g;                // row base in that buffer
  int tid = threadIdx.x, w = tid >> 6, lane = tid & 63, q = lane >> 4, c16 = lane & 15;
  __shared__ unsigned short xl[2][16 * 72];    // x tile bf16 (+8 pad)
  __shared__ unsigned short hl[2][16 * 136];   // h tile bf16 (+8 pad)
  const float* Wi = Wih + (size_t)dir * 384 * 64;
  const float* Wh = Whh + (size_t)dir * 384 * 128;
  const float* bi = bih + dir * 384;
  const float* bh = bhh + dir * 384;

  short8_t fi[6][2], fh[6][4];
  float brz[4], bni[2], bnh[2];
#pragma unroll
  for (int g = 0; g < 3; g++)
#pragma unroll
    for (int cc = 0; cc < 2; cc++) {
      int f = g * 2 + cc;
      int n0 = g * 128 + w * 32 + cc * 16;
#pragma unroll
      for (int kt = 0; kt < 2; kt++)
        fi[f][kt] = cvt8f(Wi + (size_t)(n0 + c16) * 64 + kt * 32 + q * 8);
#pragma unroll
      for (int kt = 0; kt < 4; kt++)
        fh[f][kt] = cvt8f(Wh + (size_t)(n0 + c16) * 128 + kt * 32 + q * 8);
      if (g < 2) brz[f] = bi[n0 + c16] + bh[n0 + c16];
      else { bni[cc] = bi[n0 + c16]; bnh[cc] = bh[n0 + c16]; }
    }

  float h[2][4];
#pragma unroll
  for (int cc = 0; cc < 2; cc++)
#pragma unroll
    for (int rr = 0; rr < 4; rr++) h[cc][rr] = 0.f;
  for (int i = tid; i < 16 * 136; i += 256) hl[0][i] = 0;

  int srow = tid >> 4, sc = tid & 15;          // staging/writeback roles
  {                                            // stage xl[0] for first t
    int t0 = dir ? 511 : 0;
    f32x4_t v = *reinterpret_cast<const f32x4_t*>(
        xin + ((size_t)t0 * xstr + xb0 + srow) * 64 + sc * 4);
    unsigned short* dst = &xl[0][srow * 72 + sc * 4];
    dst[0] = f2bf(v[0]); dst[1] = f2bf(v[1]); dst[2] = f2bf(v[2]); dst[3] = f2bf(v[3]);
  }
  __syncthreads();

  for (int s = 0; s < 512; s++) {
    int cur = s & 1, nxt = cur ^ 1;
    if (s > 0) {                               // Yout for h(s-1), held in hl[cur]
      int tp = dir ? (512 - s) : (s - 1);
      short8_t v = ld8(&hl[cur][srow * 136 + sc * 8]);
      *reinterpret_cast<short8_t*>(
          yout + ((size_t)tp * xstr + xb0 + srow) * 128 + sc * 8) = v;
    }
    f32x4_t xv;                                // prefetch next x tile
    if (s < 511) {
      int tn = dir ? (510 - s) : (s + 1);
      xv = *reinterpret_cast<const f32x4_t*>(
          xin + ((size_t)tn * xstr + xb0 + srow) * 64 + sc * 4);
    }
    short8_t ax[2], ah[4];
#pragma unroll
    for (int kt = 0; kt < 2; kt++) ax[kt] = ld8(&xl[cur][c16 * 72 + kt * 32 + q * 8]);
#pragma unroll
    for (int kt = 0; kt < 4; kt++) ah[kt] = ld8(&hl[cur][c16 * 136 + kt * 32 + q * 8]);
    f32x4_t aRZ[4], aNi[2], aNh[2];
#pragma unroll
    for (int f = 0; f < 4; f++) aRZ[f] = (f32x4_t){0.f, 0.f, 0.f, 0.f};
#pragma unroll
    for (int cc = 0; cc < 2; cc++) {
      aNi[cc] = (f32x4_t){0.f, 0.f, 0.f, 0.f};
      aNh[cc] = (f32x4_t){0.f, 0.f, 0.f, 0.f};
    }
#pragma unroll
    for (int kt = 0; kt < 2; kt++) {
#pragma unroll
      for (int f = 0; f < 4; f++) aRZ[f] = MFMA16(ax[kt], fi[f][kt], aRZ[f]);
#pragma unroll
      for (int cc = 0; cc < 2; cc++) aNi[cc] = MFMA16(ax[kt], fi[4 + cc][kt], aNi[cc]);
    }
#pragma unroll
    for (int kt = 0; kt < 4; kt++) {
#pragma unroll
      for (int f = 0; f < 4; f++) aRZ[f] = MFMA16(ah[kt], fh[f][kt], aRZ[f]);
#pragma unroll
      for (int cc = 0; cc < 2; cc++) aNh[cc] = MFMA16(ah[kt], fh[4 + cc][kt], aNh[cc]);
    }
#pragma unroll
    for (int cc = 0; cc < 2; cc++)
#pragma unroll
      for (int rr = 0; rr < 4; rr++) {
        float r = sigm(aRZ[cc][rr] + brz[cc]);
        float z = sigm(aRZ[2 + cc][rr] + brz[2 + cc]);
        float n = tanh_fast(aNi[cc][rr] + bni[cc] + r * (aNh[cc][rr] + bnh[cc]));
        float hn = n + z * (h[cc][rr] - n);
        h[cc][rr] = hn;
        hl[nxt][(q * 4 + rr) * 136 + w * 32 + c16 + cc * 16] = f2bf(hn);
      }
    if (s < 511) {
      unsigned short* dst = &xl[nxt][srow * 72 + sc * 4];
      dst[0] = f2bf(xv[0]); dst[1] = f2bf(xv[1]); dst[2] = f2bf(xv[2]); dst[3] = f2bf(xv[3]);
    }
    __syncthreads();
  }
  {                                            // final Yout row (step 511's h in hl[0])
    int tp = dir ? 0 : 511;
    short8_t v = ld8(&hl[0][srow * 136 + sc * 8]);
    *reinterpret_cast<short8_t*>(
        yout + ((size_t)tp * xstr + xb0 + srow) * 128 + sc * 8) = v;
  }
#pragma unroll
  for (int cc = 0; cc < 2; cc++)
#pragma unroll
    for (int rr = 0; rr < 4; rr++)
      HS[((size_t)dir * 512 + b0g + q * 4 + rr) * 128 + w * 32 + c16 + cc * 16] = h[cc][rr];
}

// ---- layer-1 scan, gi fused (K=256 = [OutF||OutB]), both dirs, pipelined ---
// grid (Bc/16, 2). Block = 512 thr (8 waves); wave w owns h-cols [w*16,+16).
// OutF = x overlay (stride 512, global rows); OutB = xc overlay (stride Bc,
// chunk-local rows). Branch-free input addressing.
__global__ __launch_bounds__(512, 1) void k_scan1(
    const unsigned short* __restrict__ OutF,  // x overlay
    const unsigned short* __restrict__ OutB,  // xc overlay
    const float* __restrict__ Wih1,           // enc_Wih1 (2,384,256) fp32
    const float* __restrict__ bih1,           // (2,384) layer1
    const float* __restrict__ Whh1,           // (2,384,128) layer1
    const float* __restrict__ bhh1,           // (2,384) layer1
    float* __restrict__ HS,
    int b_base, int Bc) {
  int dir = blockIdx.y;
  int b0l = blockIdx.x * 16;
  int tid = threadIdx.x, w = tid >> 6, lane = tid & 63, q = lane >> 4, c16 = lane & 15;
  __shared__ unsigned short il[2][16 * 264];   // input tile (256 + 8 pad)
  __shared__ unsigned short hl[2][16 * 136];
  const float* Wi = Wih1 + (size_t)dir * 384 * 256;
  const float* Wh = Whh1 + (size_t)dir * 384 * 128;
  const float* bi = bih1 + dir * 384;
  const float* bh = bhh1 + dir * 384;

  short8_t fi[3][8], fh[3][4];
  float brz[2], bni, bnh;
#pragma unroll
  for (int g = 0; g < 3; g++) {
    int n0 = g * 128 + w * 16;
#pragma unroll
    for (int kt = 0; kt < 8; kt++)
      fi[g][kt] = cvt8f(Wi + (size_t)(n0 + c16) * 256 + kt * 32 + q * 8);
#pragma unroll
    for (int kt = 0; kt < 4; kt++)
      fh[g][kt] = cvt8f(Wh + (size_t)(n0 + c16) * 128 + kt * 32 + q * 8);
    if (g < 2) brz[g] = bi[n0 + c16] + bh[n0 + c16];
    else { bni = bi[n0 + c16]; bnh = bh[n0 + c16]; }
  }

  float h[4] = {0.f, 0.f, 0.f, 0.f};
  for (int i = tid; i < 16 * 136; i += 512) hl[0][i] = 0;

  int srow = tid >> 5, sc = tid & 31;          // staging: 16 rows x 32 col-chunks
  {                                            // stage il[0] for first t
    int t0 = dir ? 511 : 0;
    short8_t v = (sc < 16)
        ? ld8(OutF + ((size_t)t0 * 512 + b_base + b0l + srow) * 128 + sc * 8)
        : ld8(OutB + ((size_t)t0 * Bc + b0l + srow) * 128 + (sc - 16) * 8);
    *reinterpret_cast<short8_t*>(&il[0][srow * 264 + sc * 8]) = v;
  }
  __syncthreads();

  for (int s = 0; s < 512; s++) {
    int cur = s & 1, nxt = cur ^ 1;
    short8_t iv;
    if (s < 511) {                             // prefetch next input tile
      int tn = dir ? (510 - s) : (s + 1);
      iv = (sc < 16)
          ? ld8(OutF + ((size_t)tn * 512 + b_base + b0l + srow) * 128 + sc * 8)
          : ld8(OutB + ((size_t)tn * Bc + b0l + srow) * 128 + (sc - 16) * 8);
    }
    f32x4_t aI[3], aH[3];
#pragma unroll
    for (int g = 0; g < 3; g++) {
      aI[g] = (f32x4_t){0.f, 0.f, 0.f, 0.f};
      aH[g] = (f32x4_t){0.f, 0.f, 0.f, 0.f};
    }
#pragma unroll
    for (int kt = 0; kt < 8; kt++) {
      short8_t a = ld8(&il[cur][c16 * 264 + kt * 32 + q * 8]);
#pragma unroll
      for (int g = 0; g < 3; g++) aI[g] = MFMA16(a, fi[g][kt], aI[g]);
    }
#pragma unroll
    for (int kt = 0; kt < 4; kt++) {
      short8_t a = ld8(&hl[cur][c16 * 136 + kt * 32 + q * 8]);
#pragma unroll
      for (int g = 0; g < 3; g++) aH[g] = MFMA16(a, fh[g][kt], aH[g]);
    }
#pragma unroll
    for (int rr = 0; rr < 4; rr++) {
      float r = sigm(aI[0][rr] + aH[0][rr] + brz[0]);
      float z = sigm(aI[1][rr] + aH[1][rr] + brz[1]);
      float n = tanh_fast(aI[2][rr] + bni + r * (aH[2][rr] + bnh));
      float hn = n + z * (h[rr] - n);
      h[rr] = hn;
      hl[nxt][(q * 4 + rr) * 136 + w * 16 + c16] = f2bf(hn);
    }
    if (s < 511)
      *reinterpret_cast<short8_t*>(&il[nxt][srow * 264 + sc * 8]) = iv;
    __syncthreads();
  }
#pragma unroll
  for (int rr = 0; rr < 4; rr++)
    HS[((size_t)(2 + dir) * 512 + b_base + b0l + q * 4 + rr) * 128 + w * 16 + c16] = h[rr];
}

// ------------------------------- decoder (verified R6) ----------------------
__global__ __launch_bounds__(256, 1) void k_dec(
    const float* __restrict__ x0save,        // (512)
    const float* __restrict__ HS,            // (4,512,128) = [l0f,l0b,l1f,l1b]
    const unsigned short* __restrict__ Whh,  // dec (2,2,384,128) bf16
    const unsigned short* __restrict__ Wih1, // dec (2,384,256) bf16
    const float* __restrict__ Wih0,          // dec (2,384,1) fp32
    const float* __restrict__ bih,           // (2,2,384)
    const float* __restrict__ bhh,           // (2,2,384)
    const float* __restrict__ fc_w,          // (256) fp32
    const float* __restrict__ fcb,           // (1)
    float* __restrict__ out) {               // (24,512)
  int b0 = blockIdx.x * 16;
  int tid = threadIdx.x, w = tid >> 6, lane = tid & 63, q = lane >> 4, c16 = lane & 15;
  __shared__ unsigned short hc0[16 * 264];
  __shared__ unsigned short hc1[16 * 264];
  __shared__ float x0s[16];
  __shared__ float fcwf[256];
  int jj = w * 32 + c16;   // actual h-column (biases, LDS addressing)
  int jw = w * 32;         // wave column base (MFMA B-frag row bases; +c16 at load)

  float hs[4][2][4];
#pragma unroll
  for (int cell = 0; cell < 4; cell++)
#pragma unroll
    for (int cc = 0; cc < 2; cc++)
#pragma unroll
      for (int rr = 0; rr < 4; rr++) {
        int row = q * 4 + rr, j = jj + cc * 16;
        float v = HS[((size_t)cell * 512 + b0 + row) * 128 + j];
        hs[cell][cc][rr] = v;
        unsigned short bv = f2bf(v);
        unsigned short* tile = (cell < 2) ? hc0 : hc1;
        tile[row * 264 + (cell & 1) * 128 + j] = bv;
      }
  if (tid < 16) x0s[tid] = x0save[b0 + tid];
  fcwf[tid] = fc_w[tid];

  float w0c[2][2][3], bi0[2][2][3], bh0[2][2][3], bi1[2][2][3], bh1[2][2][3];
#pragma unroll
  for (int d = 0; d < 2; d++)
#pragma unroll
    for (int cc = 0; cc < 2; cc++)
#pragma unroll
      for (int g = 0; g < 3; g++) {
        int col = g * 128 + jj + cc * 16;
        w0c[d][cc][g] = Wih0[d * 384 + col];
        bi0[d][cc][g] = bih[d * 384 + col];
        bh0[d][cc][g] = bhh[d * 384 + col];
        bi1[d][cc][g] = bih[(2 + d) * 384 + col];
        bh1[d][cc][g] = bhh[(2 + d) * 384 + col];
      }
  __syncthreads();

  for (int st = 0; st < 24; st++) {
    // ---- layer 0 (input = scalar x0, two cells) ----
    float hn0[2][2][4];
#pragma unroll
    for (int d = 0; d < 2; d++) {
      const unsigned short* Wd = Whh + (size_t)d * 384 * 128;
      short8_t a0[4];
#pragma unroll
      for (int kt = 0; kt < 4; kt++)
        a0[kt] = ld8(&hc0[c16 * 264 + d * 128 + kt * 32 + q * 8]);
      f32x4_t acc[6];
#pragma unroll
      for (int f = 0; f < 6; f++) acc[f] = (f32x4_t){0.f, 0.f, 0.f, 0.f};
#pragma unroll
      for (int kt = 0; kt < 4; kt++)
#pragma unroll
        for (int g = 0; g < 3; g++)
#pragma unroll
          for (int cc = 0; cc < 2; cc++) {
            int f = g * 2 + cc, n0 = g * 128 + jw + cc * 16;
            acc[f] = MFMA16(a0[kt], ld8(Wd + (size_t)(n0 + c16) * 128 + kt * 32 + q * 8), acc[f]);
          }
#pragma unroll
      for (int cc = 0; cc < 2; cc++)
#pragma unroll
        for (int rr = 0; rr < 4; rr++) {
          float xin = x0s[q * 4 + rr];
          float r = sigm(xin * w0c[d][cc][0] + bi0[d][cc][0] + acc[cc][rr] + bh0[d][cc][0]);
          float z = sigm(xin * w0c[d][cc][1] + bi0[d][cc][1] + acc[2 + cc][rr] + bh0[d][cc][1]);
          float n = tanh_fast(xin * w0c[d][cc][2] + bi0[d][cc][2] +
                              r * (acc[4 + cc][rr] + bh0[d][cc][2]));
          float hv = n + z * (hs[d][cc][rr] - n);
          hn0[d][cc][rr] = hv;
          hs[d][cc][rr] = hv;
        }
    }
    __syncthreads();
#pragma unroll
    for (int d = 0; d < 2; d++)
#pragma unroll
      for (int cc = 0; cc < 2; cc++)
#pragma unroll
        for (int rr = 0; rr < 4; rr++)
          hc0[(q * 4 + rr) * 264 + d * 128 + jj + cc * 16] = f2bf(hn0[d][cc][rr]);
    __syncthreads();

    // ---- layer 1 (input = hc0 concat, two cells) ----
    short8_t ai[8];
#pragma unroll
    for (int kt = 0; kt < 8; kt++) ai[kt] = ld8(&hc0[c16 * 264 + kt * 32 + q * 8]);
    float hn1[2][2][4];
#pragma unroll
    for (int d = 0; d < 2; d++) {
      const unsigned short* Wh = Whh + (size_t)(2 + d) * 384 * 128;
      const unsigned short* Wi = Wih1 + (size_t)d * 384 * 256;
      short8_t ah[4];
#pragma unroll
      for (int kt = 0; kt < 4; kt++)
        ah[kt] = ld8(&hc1[c16 * 264 + d * 128 + kt * 32 + q * 8]);
      f32x4_t aRZ[4], aNi[2], aNh[2];
#pragma unroll
      for (int f = 0; f < 4; f++) aRZ[f] = (f32x4_t){0.f, 0.f, 0.f, 0.f};
#pragma unroll
      for (int cc = 0; cc < 2; cc++) {
        aNi[cc] = (f32x4_t){0.f, 0.f, 0.f, 0.f};
        aNh[cc] = (f32x4_t){0.f, 0.f, 0.f, 0.f};
      }
#pragma unroll
      for (int kt = 0; kt < 8; kt++) {
#pragma unroll
        for (int f = 0; f < 4; f++) {
          int n0 = (f >> 1) * 128 + jw + (f & 1) * 16;
          aRZ[f] = MFMA16(ai[kt], ld8(Wi + (size_t)(n0 + c16) * 256 + kt * 32 + q * 8), aRZ[f]);
        }
#pragma unroll
        for (int cc = 0; cc < 2; cc++) {
          int n0 = 256 + jw + cc * 16;
          aNi[cc] = MFMA16(ai[kt], ld8(Wi + (size_t)(n0 + c16) * 256 + kt * 32 + q * 8), aNi[cc]);
        }
      }
#pragma unroll
      for (int kt = 0; kt < 4; kt++) {
#pragma unroll
        for (int f = 0; f < 4; f++) {
          int n0 = (f >> 1) * 128 + jw + (f & 1) * 16;
          aRZ[f] = MFMA16(ah[kt], ld8(Wh + (size_t)(n0 + c16) * 128 + kt * 32 + q * 8), aRZ[f]);
        }
#pragma unroll
        for (int cc = 0; cc < 2; cc++) {
          int n0 = 256 + jw + cc * 16;
          aNh[cc] = MFMA16(ah[kt], ld8(Wh + (size_t)(n0 + c16) * 128 + kt * 32 + q * 8), aNh[cc]);
        }
      }
#pragma unroll
      for (int cc = 0; cc < 2; cc++)
#pragma unroll
        for (int rr = 0; rr < 4; rr++) {
          float r = sigm(aRZ[cc][rr] + bi1[d][cc][0] + bh1[d][cc][0]);
          float z = sigm(aRZ[2 + cc][rr] + bi1[d][cc][1] + bh1[d][cc][1]);
          float n = tanh_fast(aNi[cc][rr] + bi1[d][cc][2] + r * (aNh[cc][rr] + bh1[d][cc][2]));
          float hv = n + z * (hs[2 + d][cc][rr] - n);
          hn1[d][cc][rr] = hv;
          hs[2 + d][cc][rr] = hv;
        }
    }
    __syncthreads();
#pragma unroll
    for (int d = 0; d < 2; d++)
#pragma unroll
      for (int cc = 0; cc < 2; cc++)
#pragma unroll
        for (int rr = 0; rr < 4; rr++)
          hc1[(q * 4 + rr) * 264 + d * 128 + jj + cc * 16] = f2bf(hn1[d][cc][rr]);
    __syncthreads();

    // ---- fc -> pred, feed back (wave 0 only) ----
    if (w == 0) {
      float s = 0.f;
#pragma unroll
      for (int i = 0; i < 8; i++) {
        short8_t hv = ld8(&hc1[c16 * 264 + q * 64 + i * 8]);
#pragma unroll
        for (int e = 0; e < 8; e++)
          s += bf2f((unsigned short)hv[e]) * fcwf[q * 64 + i * 8 + e];
      }
      s += __shfl_xor(s, 16);
      s += __shfl_xor(s, 32);
      if (q == 0) {
        float pred = s + fcb[0];
        x0s[c16] = pred;
        out[(size_t)st * 512 + b0 + c16] = pred;
      }
    }
    __syncthreads();
  }
}

// ---------------------------------------------------------------------------
extern "C" void kernel_launch(void* const* d_in, const int* in_sizes, int n_in,
                              void* d_out, int out_size, void* d_ws, size_t ws_size,
                              hipStream_t stream) {
  const float* x     = (const float*)d_in[0];
  const float* eWih0 = (const float*)d_in[1];
  const float* eWih1 = (const float*)d_in[2];
  const float* eWhh  = (const float*)d_in[3];
  const float* ebih  = (const float*)d_in[4];
  const float* ebhh  = (const float*)d_in[5];
  const float* dWih0 = (const float*)d_in[6];
  const float* dWih1 = (const float*)d_in[7];
  const float* dWhh  = (const float*)d_in[8];
  const float* dbih  = (const float*)d_in[9];
  const float* dbhh  = (const float*)d_in[10];
  const float* fc_w  = (const float*)d_in[11];
  const float* fc_b  = (const float*)d_in[12];
  float* out = (float*)d_out;
  (void)in_sizes; (void)n_in; (void)out_size;

  // ---- ws ladder: xc = Bc*131072 bytes (512 t x Bc rows x 64 fp32) --------
  // Bc=512 total 68.95MB == previously-passing budget; else Bc=256 (35.4MB)
  const size_t fixedB = 2048 + 1048576 + 393216 + 393216 + 4096;
  int Bc = 256;
  if (fixedB + (size_t)512 * 131072 <= ws_size) Bc = 512;

  char* ws = (char*)d_ws;
  size_t off = 0;
  auto alloc = [&](size_t bytes) -> char* {
    off = (off + 255) & ~(size_t)255;
    char* p = ws + off;
    off += bytes;
    return p;
  };
  float* x0save          = (float*)alloc(2048);
  float* HS              = (float*)alloc(1048576);
  unsigned short* bdWih1 = (unsigned short*)alloc(393216);   // 196608 elems
  unsigned short* bdWhh  = (unsigned short*)alloc(393216);   // 196608 elems
  float* xc              = (float*)alloc((size_t)Bc * 131072);

  k_prep<<<194, 256, 0, stream>>>(x, dWih1, dWhh, bdWih1, bdWhh, x0save);

  float* xm = (float*)d_in[0];   // mutable view: fwd overlay target
  const float* Whh1 = eWhh + (size_t)2 * 384 * 128;
  int nchunks = 512 / Bc;
  for (int c = 0; c < nchunks; c++) {
    int b_base = c * Bc;
    int ncopy = (512 * Bc * 16 + 255) / 256;
    k_copy<<<ncopy, 256, 0, stream>>>(x, xc, b_base, Bc);
    k_scan0d<<<dim3(Bc / 16, 2), 256, 0, stream>>>(xm, xc, eWih0, ebih, eWhh, ebhh,
                                                   HS, b_base, Bc);
    k_scan1<<<dim3(Bc / 16, 2), 512, 0, stream>>>((const unsigned short*)xm,
                                                  (const unsigned short*)xc,
                                                  eWih1, ebih + 768, Whh1,
                                                  ebhh + 768, HS, b_base, Bc);
  }
  k_dec<<<dim3(32), 256, 0, stream>>>(x0save, HS, bdWhh, bdWih1, dWih0, dbih, dbhh,
                                      fc_w, fc_b, out);
}